// Round 1
// baseline (174.077 us; speedup 1.0000x reference)
//
#include <hip/hip_runtime.h>

#define S_DIM 4096
#define C_IN  256
#define E_DIM 512
#define HD    64
#define EPSV  1e-5f

typedef __attribute__((ext_vector_type(8))) short s8v;
typedef __attribute__((ext_vector_type(4))) short s4v;
typedef __attribute__((ext_vector_type(4))) float f4v;

__device__ __forceinline__ float bf2f(unsigned short h){
  union{unsigned u; float f;} v; v.u = ((unsigned)h)<<16; return v.f;
}
__device__ __forceinline__ unsigned short f2bf(float f){
  union{float f; unsigned u;} v; v.f = f;
  unsigned r = v.u + 0x7fffu + ((v.u>>16)&1u);   // RNE
  return (unsigned short)(r>>16);
}
// [*][64]-bf16 tiles, 16B-chunk XOR swizzle on (row&7) to kill ds_read_b128 bank conflicts
__device__ __forceinline__ s8v lds_rd8(const unsigned short* b, int row, int ck){
  return *(const s8v*)&b[(row<<6) + (((ck)^(row&7))<<3)];
}
__device__ __forceinline__ void lds_wr8(unsigned short* b, int row, int ck, s8v v){
  *(s8v*)&b[(row<<6) + (((ck)^(row&7))<<3)] = v;
}

// ---- convert 5 weight matrices fp32 -> bf16 into ws (q,k,v,conv,rs contiguous) ----
__global__ __launch_bounds__(256) void k_wcvt(const float* __restrict__ w0,
    const float* __restrict__ w1, const float* __restrict__ w2,
    const float* __restrict__ w3, const float* __restrict__ w4,
    unsigned short* __restrict__ dst){
  int i = blockIdx.x*256 + threadIdx.x;   // 131072 per matrix
  int z = blockIdx.y;
  const float* s = (z==0)?w0:(z==1)?w1:(z==2)?w2:(z==3)?w3:w4;
  dst[z*(E_DIM*C_IN) + i] = f2bf(s[i]);
}

// ---- x (C,S) fp32 -> XaT (S,C) bf16 [relu(bn1)] and XrT (S,C) bf16 [raw] ----
__global__ __launch_bounds__(256) void k_prep(const float* __restrict__ x,
    const float* __restrict__ bw, const float* __restrict__ bb,
    const float* __restrict__ bm, const float* __restrict__ bvar,
    unsigned short* __restrict__ XaT, unsigned short* __restrict__ XrT){
  __shared__ float tile[32][33];
  int tid = threadIdx.x;
  int tx = tid & 31, ty = tid >> 5;
  int s0 = blockIdx.x*32, c0 = blockIdx.y*32;
  #pragma unroll
  for(int p=0;p<4;p++){
    int c = c0 + ty + p*8;
    tile[ty+p*8][tx] = x[c*S_DIM + s0 + tx];
  }
  __syncthreads();
  int cc = c0 + tx;
  float inv  = bw[cc] * rsqrtf(bvar[cc] + EPSV);
  float beta = bb[cc] - bm[cc]*inv;
  #pragma unroll
  for(int p=0;p<4;p++){
    int s = s0 + ty + p*8;
    float v = tile[tx][ty+p*8];
    float a = v*inv + beta; a = a>0.f?a:0.f;
    XaT[s*C_IN + cc] = f2bf(a);
    XrT[s*C_IN + cc] = f2bf(v);
  }
}

// ---- uniform projection GEMM: PT(s,e) = XinT(s,:) . W(e,:) + bias ----
// z=0 Q ->(S,E), z=1 K ->(S,E), z=2 V ->(E,S), z=3 conv(+cbn+relu) ->(S,E)
__global__ __launch_bounds__(256) void k_proj(
    const unsigned short* __restrict__ XaT, const unsigned short* __restrict__ XrT,
    const unsigned short* __restrict__ Wb,
    const float* __restrict__ bq, const float* __restrict__ bk,
    const float* __restrict__ bvb, const float* __restrict__ bc,
    const float* __restrict__ cw, const float* __restrict__ cbb,
    const float* __restrict__ cm, const float* __restrict__ cvv,
    unsigned short* __restrict__ QT, unsigned short* __restrict__ KT,
    unsigned short* __restrict__ Vx, unsigned short* __restrict__ CT){
  int z = blockIdx.z;
  const unsigned short* Xin = (z==3) ? XrT : XaT;
  const unsigned short* W   = Wb + z*(E_DIM*C_IN);
  const float* bias = (z==0)?bq:(z==1)?bk:(z==2)?bvb:bc;

  __shared__ unsigned short Als[128*64];
  __shared__ unsigned short Bls[64*64];
  int tid = threadIdx.x;
  int w = tid>>6, l = tid&63, g = l>>4, c16 = l&15;
  int wr = w>>1, wc = w&1;
  int s0 = blockIdx.x*128, e0 = blockIdx.y*64;

  f4v acc[4][2];
  #pragma unroll
  for(int m=0;m<4;m++)
    #pragma unroll
    for(int n=0;n<2;n++) acc[m][n] = (f4v){0.f,0.f,0.f,0.f};

  for(int kk=0;kk<4;kk++){
    __syncthreads();
    #pragma unroll
    for(int p=0;p<4;p++){
      int ck = p*256 + tid, row = ck>>3, ch = ck&7;
      s8v v = *(const s8v*)&Xin[(s0+row)*C_IN + kk*64 + ch*8];
      lds_wr8(Als, row, ch, v);
    }
    #pragma unroll
    for(int p=0;p<2;p++){
      int ck = p*256 + tid, row = ck>>3, ch = ck&7;
      s8v v = *(const s8v*)&W[(e0+row)*C_IN + kk*64 + ch*8];
      lds_wr8(Bls, row, ch, v);
    }
    __syncthreads();
    #pragma unroll
    for(int kb=0;kb<2;kb++){
      s8v bfr[2];
      #pragma unroll
      for(int n=0;n<2;n++) bfr[n] = lds_rd8(Bls, wc*32 + n*16 + c16, g + kb*4);
      #pragma unroll
      for(int m=0;m<4;m++){
        s8v af = lds_rd8(Als, wr*64 + m*16 + c16, g + kb*4);
        #pragma unroll
        for(int n=0;n<2;n++)
          acc[m][n] = __builtin_amdgcn_mfma_f32_16x16x32_bf16(af, bfr[n], acc[m][n], 0,0,0);
      }
    }
  }
  #pragma unroll
  for(int n=0;n<2;n++){
    int e = e0 + wc*32 + n*16 + c16;
    float bsv = bias[e];
    float cinv = 0.f, cbeta = 0.f;
    if(z==3){ cinv = cw[e]*rsqrtf(cvv[e]+EPSV); cbeta = cbb[e] - cm[e]*cinv; }
    #pragma unroll
    for(int m=0;m<4;m++){
      int sb = s0 + wr*64 + m*16 + g*4;
      if(z==2){
        s4v pk;
        #pragma unroll
        for(int i=0;i<4;i++) pk[i] = (short)f2bf(acc[m][n][i] + bsv);
        *(s4v*)&Vx[e*S_DIM + sb] = pk;
      } else {
        unsigned short* dst = (z==0)?QT:(z==1)?KT:CT;
        #pragma unroll
        for(int i=0;i<4;i++){
          float vv = acc[m][n][i] + bsv;
          if(z==3){ vv = vv*cinv + cbeta; vv = vv>0.f?vv:0.f; }
          dst[(sb+i)*E_DIM + e] = f2bf(vv);
        }
      }
    }
  }
}

// ---- flash attention + fuse(gamma*out + conv_path) -> fusedT (S,E) bf16 ----
__global__ __launch_bounds__(256) void k_attn(
    const unsigned short* __restrict__ QT, const unsigned short* __restrict__ KT,
    const unsigned short* __restrict__ Vx, const unsigned short* __restrict__ CT,
    const float* __restrict__ gamma, const float* __restrict__ temp,
    unsigned short* __restrict__ fusedT){
  __shared__ unsigned short Kls[64*64];
  __shared__ unsigned short Vls[64*64];
  __shared__ unsigned short Pls[4][16*64];
  int tid = threadIdx.x;
  int w = tid>>6, l = tid&63, g = l>>4, c16 = l&15;
  int h = blockIdx.y;
  int q0 = blockIdx.x*64 + w*16;     // each wave owns 16 query rows
  float invT = 1.0f / temp[0];

  // Q fragments live in registers for the whole kernel
  s8v qf0 = *(const s8v*)&QT[(q0+c16)*E_DIM + h*HD + g*8];
  s8v qf1 = *(const s8v*)&QT[(q0+c16)*E_DIM + h*HD + g*8 + 32];

  f4v oacc[4];
  #pragma unroll
  for(int dt=0;dt<4;dt++) oacc[dt] = (f4v){0.f,0.f,0.f,0.f};
  float mrun[4] = {-1e30f,-1e30f,-1e30f,-1e30f};
  float lrun[4] = {0.f,0.f,0.f,0.f};
  unsigned short* Pw = Pls[w];

  for(int t=0;t<64;t++){
    int sK = t*64;
    __syncthreads();
    #pragma unroll
    for(int p=0;p<2;p++){                 // K tile: 64 keys x 64 d
      int ck = p*256 + tid, row = ck>>3, ch = ck&7;
      s8v v = *(const s8v*)&KT[(sK+row)*E_DIM + h*HD + ch*8];
      lds_wr8(Kls, row, ch, v);
    }
    #pragma unroll
    for(int p=0;p<2;p++){                 // V tile: Vt[d][key]
      int ck = p*256 + tid, row = ck>>3, ch = ck&7;
      s8v v = *(const s8v*)&Vx[(h*HD+row)*S_DIM + sK + ch*8];
      lds_wr8(Vls, row, ch, v);
    }
    __syncthreads();

    // S = Q K^T : acc[kt] rows=q (g*4+i), cols=key (c16 + 16*kt)
    f4v sacc[4];
    #pragma unroll
    for(int kt=0;kt<4;kt++) sacc[kt] = (f4v){0.f,0.f,0.f,0.f};
    #pragma unroll
    for(int kt=0;kt<4;kt++){
      int r = kt*16 + c16;
      s8v kf0 = lds_rd8(Kls, r, g);
      s8v kf1 = lds_rd8(Kls, r, g+4);
      sacc[kt] = __builtin_amdgcn_mfma_f32_16x16x32_bf16(qf0, kf0, sacc[kt],0,0,0);
      sacc[kt] = __builtin_amdgcn_mfma_f32_16x16x32_bf16(qf1, kf1, sacc[kt],0,0,0);
    }
    // online softmax: row lives across the 16 lanes of a g-group
    float tm[4] = {-1e30f,-1e30f,-1e30f,-1e30f};
    #pragma unroll
    for(int kt=0;kt<4;kt++)
      #pragma unroll
      for(int i=0;i<4;i++){
        float sc = sacc[kt][i]*invT;
        sacc[kt][i] = sc;
        tm[i] = fmaxf(tm[i], sc);
      }
    #pragma unroll
    for(int off=8; off>=1; off>>=1)
      #pragma unroll
      for(int i=0;i<4;i++)
        tm[i] = fmaxf(tm[i], __shfl_xor(tm[i], off));
    float scl[4], ts[4];
    #pragma unroll
    for(int i=0;i<4;i++){
      float mn = fmaxf(mrun[i], tm[i]);
      scl[i] = __expf(mrun[i]-mn);
      mrun[i] = mn;
      ts[i] = 0.f;
    }
    #pragma unroll
    for(int kt=0;kt<4;kt++){
      int colb = c16 + kt*16;
      int ckk = colb>>3, cre = colb&7;
      #pragma unroll
      for(int i=0;i<4;i++){
        float pv = __expf(sacc[kt][i] - mrun[i]);
        ts[i] += pv;
        int row = g*4+i;
        Pw[(row<<6) + ((ckk^(row&7))<<3) + cre] = f2bf(pv);
      }
    }
    #pragma unroll
    for(int off=8; off>=1; off>>=1)
      #pragma unroll
      for(int i=0;i<4;i++)
        ts[i] += __shfl_xor(ts[i], off);
    #pragma unroll
    for(int i=0;i<4;i++) lrun[i] = lrun[i]*scl[i] + ts[i];
    #pragma unroll
    for(int dt=0;dt<4;dt++)
      #pragma unroll
      for(int i=0;i<4;i++) oacc[dt][i] *= scl[i];
    // O += P V  (P re-read from per-wave LDS in A-fragment layout)
    #pragma unroll
    for(int kb=0;kb<2;kb++){
      s8v pf = lds_rd8(Pw, c16, g + kb*4);
      #pragma unroll
      for(int dt=0;dt<4;dt++){
        s8v vf = lds_rd8(Vls, dt*16 + c16, g + kb*4);
        oacc[dt] = __builtin_amdgcn_mfma_f32_16x16x32_bf16(pf, vf, oacc[dt],0,0,0);
      }
    }
  }
  // epilogue: fusedT[s][e] = gamma*O/l + conv_path
  float ga = gamma[0];
  float rl[4];
  #pragma unroll
  for(int i=0;i<4;i++) rl[i] = 1.0f/lrun[i];
  #pragma unroll
  for(int dt=0;dt<4;dt++){
    int e = h*HD + dt*16 + c16;
    #pragma unroll
    for(int i=0;i<4;i++){
      int s = q0 + g*4 + i;
      float o = oacc[dt][i]*rl[i]*ga + bf2f(CT[s*E_DIM + e]);
      fusedT[s*E_DIM + e] = f2bf(o);
    }
  }
}

// ---- final: out(c,s) = gelu(rbn(rs_w . fused + rs_b)) fp32 ----
__global__ __launch_bounds__(256) void k_final(
    const unsigned short* __restrict__ Wrs,
    const unsigned short* __restrict__ fusedT,
    const float* __restrict__ rsb,
    const float* __restrict__ rw, const float* __restrict__ rbb,
    const float* __restrict__ rm, const float* __restrict__ rv,
    float* __restrict__ out){
  __shared__ unsigned short Als[64*64];
  __shared__ unsigned short Bls[128*64];
  int tid = threadIdx.x;
  int w = tid>>6, l = tid&63, g = l>>4, c16 = l&15;
  int wr = w>>1, wc = w&1;
  int sB0 = blockIdx.x*128, c0 = blockIdx.y*64;
  f4v acc[2][4];
  #pragma unroll
  for(int m=0;m<2;m++)
    #pragma unroll
    for(int n=0;n<4;n++) acc[m][n]=(f4v){0.f,0.f,0.f,0.f};
  for(int kk=0;kk<8;kk++){
    __syncthreads();
    #pragma unroll
    for(int p=0;p<2;p++){
      int ck = p*256+tid, row=ck>>3, ch=ck&7;
      s8v v = *(const s8v*)&Wrs[(c0+row)*E_DIM + kk*64 + ch*8];
      lds_wr8(Als, row, ch, v);
    }
    #pragma unroll
    for(int p=0;p<4;p++){
      int ck = p*256+tid, row=ck>>3, ch=ck&7;
      s8v v = *(const s8v*)&fusedT[(sB0+row)*E_DIM + kk*64 + ch*8];
      lds_wr8(Bls, row, ch, v);
    }
    __syncthreads();
    #pragma unroll
    for(int kb=0;kb<2;kb++){
      s8v af[2]; s8v bfr[4];
      #pragma unroll
      for(int m=0;m<2;m++) af[m] = lds_rd8(Als, wr*32 + m*16 + c16, g + kb*4);
      #pragma unroll
      for(int n=0;n<4;n++) bfr[n] = lds_rd8(Bls, wc*64 + n*16 + c16, g + kb*4);
      #pragma unroll
      for(int m=0;m<2;m++)
        #pragma unroll
        for(int n=0;n<4;n++)
          acc[m][n] = __builtin_amdgcn_mfma_f32_16x16x32_bf16(af[m], bfr[n], acc[m][n],0,0,0);
    }
  }
  #pragma unroll
  for(int m=0;m<2;m++){
    #pragma unroll
    for(int i=0;i<4;i++){
      int c = c0 + wr*32 + m*16 + g*4 + i;
      float bias = rsb[c];
      float rinv = rw[c]*rsqrtf(rv[c]+EPSV);
      float rbeta = rbb[c] - rm[c]*rinv;
      #pragma unroll
      for(int n=0;n<4;n++){
        int s = sB0 + wc*64 + n*16 + c16;
        float vv = acc[m][n][i] + bias;
        vv = vv*rinv + rbeta;
        out[c*S_DIM + s] = 0.5f*vv*(1.0f + erff(vv*0.70710678118f));
      }
    }
  }
}

extern "C" void kernel_launch(void* const* d_in, const int* in_sizes, int n_in,
                              void* d_out, int out_size, void* d_ws, size_t ws_size,
                              hipStream_t stream){
  const float* x     = (const float*)d_in[0];
  const float* bn1w  = (const float*)d_in[1];
  const float* bn1b  = (const float*)d_in[2];
  const float* bn1m  = (const float*)d_in[3];
  const float* bn1v  = (const float*)d_in[4];
  const float* Wq    = (const float*)d_in[5];
  const float* bq    = (const float*)d_in[6];
  const float* Wk    = (const float*)d_in[7];
  const float* bk    = (const float*)d_in[8];
  const float* Wv    = (const float*)d_in[9];
  const float* bv    = (const float*)d_in[10];
  const float* gamma = (const float*)d_in[11];
  const float* temp  = (const float*)d_in[12];
  const float* convw = (const float*)d_in[13];
  const float* convb = (const float*)d_in[14];
  const float* cbnw  = (const float*)d_in[15];
  const float* cbnb  = (const float*)d_in[16];
  const float* cbnm  = (const float*)d_in[17];
  const float* cbnv  = (const float*)d_in[18];
  const float* rsw   = (const float*)d_in[19];
  const float* rsbp  = (const float*)d_in[20];
  const float* rbnw  = (const float*)d_in[21];
  const float* rbnb  = (const float*)d_in[22];
  const float* rbnm  = (const float*)d_in[23];
  const float* rbnv  = (const float*)d_in[24];
  float* out = (float*)d_out;

  unsigned short* ws  = (unsigned short*)d_ws;
  unsigned short* XaT = ws;                          // (S,C) bf16
  unsigned short* XrT = XaT + S_DIM*C_IN;            // (S,C) bf16
  unsigned short* Wb  = XrT + S_DIM*C_IN;            // q,k,v,conv weights bf16
  unsigned short* Wrs = Wb + 4*E_DIM*C_IN;           // rs weight bf16 (256x512)
  unsigned short* QT  = Wrs + C_IN*E_DIM;            // (S,E)
  unsigned short* KT  = QT + S_DIM*E_DIM;            // (S,E)
  unsigned short* Vx  = KT + S_DIM*E_DIM;            // (E,S)
  unsigned short* CT  = Vx + S_DIM*E_DIM;            // (S,E) conv path
  unsigned short* fusedT = CT + S_DIM*E_DIM;         // (S,E)

  k_wcvt<<<dim3(512,5),256,0,stream>>>(Wq, Wk, Wv, convw, rsw, Wb);
  k_prep<<<dim3(128,8),256,0,stream>>>(x, bn1w, bn1b, bn1m, bn1v, XaT, XrT);
  k_proj<<<dim3(32,8,4),256,0,stream>>>(XaT, XrT, Wb, bq, bk, bv, convb,
                                        cbnw, cbnb, cbnm, cbnv, QT, KT, Vx, CT);
  k_attn<<<dim3(64,8),256,0,stream>>>(QT, KT, Vx, CT, gamma, temp, fusedT);
  k_final<<<dim3(32,4),256,0,stream>>>(Wrs, fusedT, rsbp, rbnw, rbnb, rbnm, rbnv, out);
}